// Round 1
// baseline (248.068 us; speedup 1.0000x reference)
//
#include <hip/hip_runtime.h>
#include <math.h>

// B=64 rows, T=524288 cols, f32. loss = mean_i ||pred_i - true_i||_2.
// Harness-verified best (247.4 us recorded); resubmitted after infra-failed
// bench to recover counters. Streaming roofline: 268.4 MB read -> ~43 us at
// 6.3 TB/s. nt loads avoid L3 allocation churn against the harness's dirty
// restore-resident lines (prior-session R3 win).

#define B_ROWS 64
#define T_ELEMS 524288
#define CHUNKS_PER_ROW 64           // 4096 blocks total
#define BLOCK 256

typedef float f4 __attribute__((ext_vector_type(4)));

// T/4 = 131072 f4/row/input; per chunk 2048; per thread 8 per input.

__global__ __launch_bounds__(BLOCK) void sdtw_stage1(
    const f4* __restrict__ yp, const f4* __restrict__ yt,
    float* __restrict__ partial)
{
    const int row   = blockIdx.x >> 6;          // / CHUNKS_PER_ROW
    const int chunk = blockIdx.x & (CHUNKS_PER_ROW - 1);
    const int T4        = T_ELEMS / 4;          // 131072
    const int per_chunk = T4 / CHUNKS_PER_ROW;  // 2048 f4
    const size_t base = (size_t)row * T4 + (size_t)chunk * per_chunk;

    f4 A[8], Bv[8];
    const size_t idx = base + threadIdx.x;
#pragma unroll
    for (int i = 0; i < 8; ++i)
        A[i]  = __builtin_nontemporal_load(&yp[idx + (size_t)i * BLOCK]);
#pragma unroll
    for (int i = 0; i < 8; ++i)
        Bv[i] = __builtin_nontemporal_load(&yt[idx + (size_t)i * BLOCK]);

    float acc0 = 0.0f, acc1 = 0.0f;
#pragma unroll
    for (int i = 0; i < 8; ++i) {
        f4 d = A[i] - Bv[i];
        float p = d.x * d.x + d.y * d.y + d.z * d.z + d.w * d.w;
        if (i & 1) acc1 += p; else acc0 += p;
    }
    float acc = acc0 + acc1;

    // wave-64 shuffle reduction
    for (int off = 32; off > 0; off >>= 1)
        acc += __shfl_down(acc, off, 64);

    __shared__ float s[BLOCK / 64];
    const int lane = threadIdx.x & 63;
    const int wave = threadIdx.x >> 6;
    if (lane == 0) s[wave] = acc;
    __syncthreads();
    if (threadIdx.x == 0) {
        float r = 0.0f;
#pragma unroll
        for (int w = 0; w < BLOCK / 64; ++w) r += s[w];
        partial[blockIdx.x] = r;   // layout: row*CHUNKS_PER_ROW + chunk
    }
}

__global__ __launch_bounds__(64) void sdtw_stage2(
    const float* __restrict__ partial, float* __restrict__ out)
{
    // one wave: thread i handles row i
    float acc = 0.0f;
#pragma unroll
    for (int k = 0; k < CHUNKS_PER_ROW; ++k)
        acc += partial[threadIdx.x * CHUNKS_PER_ROW + k];
    float norm = sqrtf(acc);
    for (int off = 32; off > 0; off >>= 1)
        norm += __shfl_down(norm, off, 64);
    if (threadIdx.x == 0)
        out[0] = norm * (1.0f / (float)B_ROWS);
}

extern "C" void kernel_launch(void* const* d_in, const int* in_sizes, int n_in,
                              void* d_out, int out_size, void* d_ws, size_t ws_size,
                              hipStream_t stream) {
    const f4* yp = (const f4*)d_in[0];
    const f4* yt = (const f4*)d_in[1];
    float* partial = (float*)d_ws;   // 4096 floats = 16 KB
    float* out = (float*)d_out;

    sdtw_stage1<<<B_ROWS * CHUNKS_PER_ROW, BLOCK, 0, stream>>>(yp, yt, partial);
    sdtw_stage2<<<1, 64, 0, stream>>>(partial, out);
}

// Round 2
// 246.496 us; speedup vs baseline: 1.0064x; 1.0064x over previous
//
#include <hip/hip_runtime.h>
#include <math.h>

// B=64 rows, T=524288 cols, f32. loss = mean_i ||pred_i - true_i||_2.
// R2: single-residency-batch grid (1024 blocks = 4 wg/CU x 256 CU, zero
// dispatch tail vs 4096-block 4-batch), 4-iter per-thread loop of (8+8)
// interleaved nt f4 loads; stage2 reads partials as f4.
// Roofline: 268.4 MB read -> ~43 us @ 6.3 TB/s. Harness restore fills
// (~78 us each, 86% peak) dominate the measured 248 us and are untouchable.

#define B_ROWS 64
#define T_ELEMS 524288
#define CHUNKS_PER_ROW 16           // 1024 blocks total
#define BLOCK 256
#define ITERS 4                     // per thread: 4 x 8 f4 per input

typedef float f4 __attribute__((ext_vector_type(4)));

// T/4 = 131072 f4/row/input; per chunk 8192 f4; per thread 32 f4 per input.

__global__ __launch_bounds__(BLOCK) void sdtw_stage1(
    const f4* __restrict__ yp, const f4* __restrict__ yt,
    float* __restrict__ partial)
{
    const int row   = blockIdx.x >> 4;          // / CHUNKS_PER_ROW
    const int chunk = blockIdx.x & (CHUNKS_PER_ROW - 1);
    const int T4        = T_ELEMS / 4;          // 131072
    const int per_chunk = T4 / CHUNKS_PER_ROW;  // 8192 f4
    const size_t base = (size_t)row * T4 + (size_t)chunk * per_chunk
                      + threadIdx.x;

    float acc = 0.0f;
    for (int it = 0; it < ITERS; ++it) {
        const size_t o = base + (size_t)it * (8 * BLOCK);
        f4 A[8], Bv[8];
        // Interleave A/B so in-order vmcnt completion lets the first
        // subtract start after 2 loads land, not 9.
#pragma unroll
        for (int j = 0; j < 8; ++j) {
            A[j]  = __builtin_nontemporal_load(&yp[o + (size_t)j * BLOCK]);
            Bv[j] = __builtin_nontemporal_load(&yt[o + (size_t)j * BLOCK]);
        }
        float a0 = 0.0f, a1 = 0.0f;
#pragma unroll
        for (int j = 0; j < 8; ++j) {
            f4 d = A[j] - Bv[j];
            float p = d.x * d.x + d.y * d.y + d.z * d.z + d.w * d.w;
            if (j & 1) a1 += p; else a0 += p;
        }
        acc += a0 + a1;
    }

    // wave-64 shuffle reduction
    for (int off = 32; off > 0; off >>= 1)
        acc += __shfl_down(acc, off, 64);

    __shared__ float s[BLOCK / 64];
    const int lane = threadIdx.x & 63;
    const int wave = threadIdx.x >> 6;
    if (lane == 0) s[wave] = acc;
    __syncthreads();
    if (threadIdx.x == 0) {
        float r = 0.0f;
#pragma unroll
        for (int w = 0; w < BLOCK / 64; ++w) r += s[w];
        partial[blockIdx.x] = r;   // layout: row*CHUNKS_PER_ROW + chunk
    }
}

__global__ __launch_bounds__(64) void sdtw_stage2(
    const float* __restrict__ partial, float* __restrict__ out)
{
    // one wave: thread i handles row i; 16 partials/row read as 4 x f4
    const f4* p4 = (const f4*)partial;           // 256 f4 total
    f4 v0 = p4[threadIdx.x * 4 + 0];
    f4 v1 = p4[threadIdx.x * 4 + 1];
    f4 v2 = p4[threadIdx.x * 4 + 2];
    f4 v3 = p4[threadIdx.x * 4 + 3];
    f4 vs = (v0 + v1) + (v2 + v3);
    float accf = (vs.x + vs.y) + (vs.z + vs.w);
    float norm = sqrtf(accf);
    for (int off = 32; off > 0; off >>= 1)
        norm += __shfl_down(norm, off, 64);
    if (threadIdx.x == 0)
        out[0] = norm * (1.0f / (float)B_ROWS);
}

extern "C" void kernel_launch(void* const* d_in, const int* in_sizes, int n_in,
                              void* d_out, int out_size, void* d_ws, size_t ws_size,
                              hipStream_t stream) {
    const f4* yp = (const f4*)d_in[0];
    const f4* yt = (const f4*)d_in[1];
    float* partial = (float*)d_ws;   // 1024 floats = 4 KB
    float* out = (float*)d_out;

    sdtw_stage1<<<B_ROWS * CHUNKS_PER_ROW, BLOCK, 0, stream>>>(yp, yt, partial);
    sdtw_stage2<<<1, 64, 0, stream>>>(partial, out);
}